// Round 20
// baseline (369.465 us; speedup 1.0000x reference)
//
#include <hip/hip_runtime.h>
#include <hip/hip_bf16.h>

#define HD 64        // hidden == out dim
#define CH 8192      // edges per bin1 block
#define BKT_SHIFT 10 // 1024 nodes per bucket
#define SRC_BITS 17  // N=100000 < 2^17 -> {dstlocal:10 | src:17} fits in 27 bits
#define MAXBLK 256   // >= NBLK = ceil(E/CH) = 196

typedef __attribute__((ext_vector_type(8))) short bf16x8;
typedef __attribute__((ext_vector_type(4))) float f32x4;
typedef __attribute__((ext_vector_type(4))) unsigned int u32x4;

#define WAITALL do { asm volatile("s_waitcnt vmcnt(0)" ::: "memory"); \
                     __builtin_amdgcn_sched_barrier(0); } while (0)

__device__ inline unsigned short f2bf(float x) {
  unsigned u = __float_as_uint(x);
  unsigned r = u + 0x7FFF + ((u >> 16) & 1);
  return (unsigned short)(r >> 16);
}
__device__ inline float bf2f(unsigned short h) {
  return __uint_as_float(((unsigned)h) << 16);
}

// ---------------- W fragment prep: lane-indexed MFMA B-frags in global -------
__global__ __launch_bounds__(256) void k_wprep(const float* __restrict__ W1,
                                               const float* __restrict__ W2,
                                               unsigned short* __restrict__ Wf1,
                                               unsigned short* __restrict__ Wf2hi,
                                               unsigned short* __restrict__ Wf2lo) {
  int idx = blockIdx.x * blockDim.x + threadIdx.x;
  if (idx < 256 * 64) {
    int k = idx >> 6, c = idx & 63;
    float w = W1[idx];
    int ks = k >> 5, r = k & 31, h2 = r >> 3, j = r & 7;
    int f = c >> 4, r16c = c & 15;
    int pos = (((ks * 4 + f) * 64) + h2 * 16 + r16c) * 8 + j;
    Wf1[pos] = f2bf(w);
  } else if (idx < 256 * 64 + 64 * 64) {
    int i2 = idx - 256 * 64;
    int k = i2 >> 6, c = i2 & 63;
    float w = W2[i2];
    int ks = k >> 5, r = k & 31, h2 = r >> 3, j = r & 7;
    int f = c >> 4, r16c = c & 15;
    int pos = (((ks * 4 + f) * 64) + h2 * 16 + r16c) * 8 + j;
    unsigned short hi = f2bf(w);
    Wf2hi[pos] = hi;
    Wf2lo[pos] = f2bf(w - bf2f(hi));
  }
}

// ---------------- binning pass 1 (both graphs): block-local bucket sort ------
__global__ __launch_bounds__(256) void k_bin1(const int* __restrict__ src0,
                                              const int* __restrict__ dst0,
                                              const int* __restrict__ src1,
                                              const int* __restrict__ dst1,
                                              int* __restrict__ tmp,
                                              int* __restrict__ counts,
                                              int* __restrict__ offsets,
                                              int NB, int NBLK, int E) {
  __shared__ int hist[128];
  __shared__ int pref[128];
  __shared__ int lofs[128];
  __shared__ int stage[CH];  // 32 KB
  const int g = blockIdx.x / NBLK;
  const int blk = blockIdx.x % NBLK;
  const int* __restrict__ src = g ? src1 : src0;
  const int* __restrict__ dst = g ? dst1 : dst0;
  int* __restrict__ tmpg = tmp + (size_t)g * NBLK * CH;
  int* __restrict__ cntg = counts + (size_t)g * NB * NBLK;
  int* __restrict__ offg = offsets + (size_t)g * NB * NBLK;
  const int e0 = blk * CH;
  const int len = min(CH, E - e0);
  const int t = threadIdx.x;

  for (int i = t; i < 128; i += 256) hist[i] = 0;
  __syncthreads();
  int dreg[CH / 256];
#pragma unroll
  for (int it = 0; it < CH / 256; ++it) {
    int i = t + it * 256;
    if (i < len) {
      int d = dst[e0 + i];
      dreg[it] = d;
      atomicAdd(&hist[d >> BKT_SHIFT], 1);
    }
  }
  __syncthreads();
  if (t < 128) pref[t] = hist[t];
  __syncthreads();
  for (int off = 1; off < 128; off <<= 1) {
    int v = 0;
    if (t < 128 && t >= off) v = pref[t - off];
    __syncthreads();
    if (t < 128) pref[t] += v;
    __syncthreads();
  }
  if (t < NB) {
    int ex = pref[t] - hist[t];
    lofs[t] = ex;
    cntg[t * NBLK + blk] = hist[t];   // [bucket][block]
    offg[t * NBLK + blk] = ex;
  }
  __syncthreads();
#pragma unroll
  for (int it = 0; it < CH / 256; ++it) {
    int i = t + it * 256;
    if (i < len) {
      int d = dreg[it], s = src[e0 + i];
      int slot = atomicAdd(&lofs[d >> BKT_SHIFT], 1);
      stage[slot] = ((d & ((1 << BKT_SHIFT) - 1)) << SRC_BITS) | s;
    }
  }
  __syncthreads();
  int nv = len >> 2;
  for (int i = t; i < nv; i += 256) ((int4*)(tmpg + e0))[i] = ((const int4*)stage)[i];
  for (int i = (nv << 2) + t; i < len; i += 256) tmpg[e0 + i] = stage[i];
}

// ---------------- bucket totals + exclusive scan (one block per graph) -------
__global__ __launch_bounds__(128) void k_bscan(const int* __restrict__ counts,
                                               int* __restrict__ bucket_base,
                                               int* __restrict__ row_start,
                                               int NB, int NBLK, int N, int E) {
  __shared__ int sh[128];
  const int g = blockIdx.x;
  const int* __restrict__ cntg = counts + (size_t)g * NB * NBLK;
  int* __restrict__ bbg = bucket_base + g * (NB + 1);
  int* __restrict__ rsg = row_start + (size_t)g * (N + 1);
  int t = threadIdx.x;
  int v = 0;
  if (t < NB) {
    const int* p = cntg + t * NBLK;
    for (int i = 0; i < NBLK; ++i) v += p[i];
  }
  sh[t] = v;
  __syncthreads();
  for (int off = 1; off < 128; off <<= 1) {
    int x = (t >= off) ? sh[t - off] : 0;
    __syncthreads();
    sh[t] += x;
    __syncthreads();
  }
  if (t < NB) bbg[t] = sh[t] - v;  // exclusive
  if (t == 0) {
    bbg[NB] = E;
    rsg[N] = E;
  }
}

// ---------------- merged bin2 (both graphs): hist + scan + place -------------
__global__ __launch_bounds__(1024) void k_bin2m(const int* __restrict__ tmp,
                                                const int* __restrict__ counts,
                                                const int* __restrict__ offsets,
                                                const int* __restrict__ bucket_base,
                                                int* __restrict__ row_start,
                                                float* __restrict__ dinv,
                                                int* __restrict__ recs, int N, int NB,
                                                int NBLK, int E) {
  __shared__ int h[1 << BKT_SHIFT];
  __shared__ int lcur[1 << BKT_SHIFT];
  __shared__ int scnt[MAXBLK], soff[MAXBLK];
  const int g = blockIdx.x / NB;
  const int b = blockIdx.x % NB;
  const int* __restrict__ tmpg = tmp + (size_t)g * NBLK * CH;
  const int* __restrict__ cntg = counts + (size_t)g * NB * NBLK;
  const int* __restrict__ offg = offsets + (size_t)g * NB * NBLK;
  const int* __restrict__ bbg = bucket_base + g * (NB + 1);
  int* __restrict__ rsg = row_start + (size_t)g * (N + 1);
  float* __restrict__ dig = dinv + (size_t)g * N;
  int* __restrict__ recg = recs + (size_t)g * E;
  const int t = threadIdx.x;
  const int node0 = b << BKT_SHIFT;
  const int lane = t & 63, w = t >> 6;

  h[t] = 0;
  for (int i = t; i < NBLK; i += 1024) {
    scnt[i] = cntg[b * NBLK + i];
    soff[i] = offg[b * NBLK + i];
  }
  __syncthreads();
  for (int blk = w; blk < NBLK; blk += 16) {
    int cnt = scnt[blk];
    const int* p = tmpg + blk * CH + soff[blk];
    for (int j = lane; j < cnt; j += 64) atomicAdd(&h[p[j] >> SRC_BITS], 1);
  }
  __syncthreads();
  int deg = h[t];
  __syncthreads();
  for (int off = 1; off < 1024; off <<= 1) {
    int x = (t >= off) ? h[t - off] : 0;
    __syncthreads();
    h[t] += x;
    __syncthreads();
  }
  int base = bbg[b] + h[t] - deg;
  lcur[t] = base;
  int n = node0 + t;
  if (n < N) {
    rsg[n] = base;
    dig[n] = rsqrtf((float)deg + 1.0f);
  }
  __syncthreads();
  for (int blk = w; blk < NBLK; blk += 16) {
    int cnt = scnt[blk];
    const int* p = tmpg + blk * CH + soff[blk];
    for (int j = lane; j < cnt; j += 64) {
      int rec = p[j];
      int d = rec >> SRC_BITS;
      int s = rec & ((1 << SRC_BITS) - 1);
      int slot = atomicAdd(&lcur[d], 1);
      recg[slot] = s;
    }
  }
}

// ---------------- GEMM1 fp32 K=256: asm-batched loads (early-clobber), no LDS
__global__ __launch_bounds__(256) void k_gemm1(const float* __restrict__ X0,
                                               const float* __restrict__ X1,
                                               const unsigned short* __restrict__ Wf1,
                                               unsigned short* __restrict__ Hb, int N,
                                               int gPer) {
  const int tid = threadIdx.x;
  const int g = blockIdx.x / gPer;
  const int bblk = blockIdx.x % gPer;
  const float* __restrict__ Xv = g ? X1 : X0;
  const int lane = tid & 63;
  const int wv = tid >> 6;
  const int r16 = lane & 15;
  const int half = lane >> 4;
  const int row = bblk * 64 + wv * 16 + r16;
  const int rowc = min(row, N - 1);

  unsigned long long xa =
      (unsigned long long)(const void*)(Xv + (size_t)rowc * 256 + half * 8);
  f32x4 a[16];
  asm volatile(
      "global_load_dwordx4 %0, %16, off\n\t"
      "global_load_dwordx4 %1, %16, off offset:16\n\t"
      "global_load_dwordx4 %2, %16, off offset:128\n\t"
      "global_load_dwordx4 %3, %16, off offset:144\n\t"
      "global_load_dwordx4 %4, %16, off offset:256\n\t"
      "global_load_dwordx4 %5, %16, off offset:272\n\t"
      "global_load_dwordx4 %6, %16, off offset:384\n\t"
      "global_load_dwordx4 %7, %16, off offset:400\n\t"
      "global_load_dwordx4 %8, %16, off offset:512\n\t"
      "global_load_dwordx4 %9, %16, off offset:528\n\t"
      "global_load_dwordx4 %10, %16, off offset:640\n\t"
      "global_load_dwordx4 %11, %16, off offset:656\n\t"
      "global_load_dwordx4 %12, %16, off offset:768\n\t"
      "global_load_dwordx4 %13, %16, off offset:784\n\t"
      "global_load_dwordx4 %14, %16, off offset:896\n\t"
      "global_load_dwordx4 %15, %16, off offset:912\n\t"
      : "=&v"(a[0]), "=&v"(a[1]), "=&v"(a[2]), "=&v"(a[3]), "=&v"(a[4]),
        "=&v"(a[5]), "=&v"(a[6]), "=&v"(a[7]), "=&v"(a[8]), "=&v"(a[9]),
        "=&v"(a[10]), "=&v"(a[11]), "=&v"(a[12]), "=&v"(a[13]), "=&v"(a[14]),
        "=&v"(a[15])
      : "v"(xa));

  const unsigned long long wb = (unsigned long long)(const void*)Wf1 + lane * 16;
  bf16x8 B[32];
  asm volatile(
      "global_load_dwordx4 %0, %16, off\n\t"
      "global_load_dwordx4 %1, %16, off offset:1024\n\t"
      "global_load_dwordx4 %2, %16, off offset:2048\n\t"
      "global_load_dwordx4 %3, %16, off offset:3072\n\t"
      "global_load_dwordx4 %4, %17, off\n\t"
      "global_load_dwordx4 %5, %17, off offset:1024\n\t"
      "global_load_dwordx4 %6, %17, off offset:2048\n\t"
      "global_load_dwordx4 %7, %17, off offset:3072\n\t"
      "global_load_dwordx4 %8, %18, off\n\t"
      "global_load_dwordx4 %9, %18, off offset:1024\n\t"
      "global_load_dwordx4 %10, %18, off offset:2048\n\t"
      "global_load_dwordx4 %11, %18, off offset:3072\n\t"
      "global_load_dwordx4 %12, %19, off\n\t"
      "global_load_dwordx4 %13, %19, off offset:1024\n\t"
      "global_load_dwordx4 %14, %19, off offset:2048\n\t"
      "global_load_dwordx4 %15, %19, off offset:3072\n\t"
      : "=&v"(B[0]), "=&v"(B[1]), "=&v"(B[2]), "=&v"(B[3]), "=&v"(B[4]),
        "=&v"(B[5]), "=&v"(B[6]), "=&v"(B[7]), "=&v"(B[8]), "=&v"(B[9]),
        "=&v"(B[10]), "=&v"(B[11]), "=&v"(B[12]), "=&v"(B[13]), "=&v"(B[14]),
        "=&v"(B[15])
      : "v"(wb), "v"(wb + 4096), "v"(wb + 8192), "v"(wb + 12288));

  WAITALL;  // A + B[0..15] ready; nothing else outstanding

  asm volatile(
      "global_load_dwordx4 %0, %16, off\n\t"
      "global_load_dwordx4 %1, %16, off offset:1024\n\t"
      "global_load_dwordx4 %2, %16, off offset:2048\n\t"
      "global_load_dwordx4 %3, %16, off offset:3072\n\t"
      "global_load_dwordx4 %4, %17, off\n\t"
      "global_load_dwordx4 %5, %17, off offset:1024\n\t"
      "global_load_dwordx4 %6, %17, off offset:2048\n\t"
      "global_load_dwordx4 %7, %17, off offset:3072\n\t"
      "global_load_dwordx4 %8, %18, off\n\t"
      "global_load_dwordx4 %9, %18, off offset:1024\n\t"
      "global_load_dwordx4 %10, %18, off offset:2048\n\t"
      "global_load_dwordx4 %11, %18, off offset:3072\n\t"
      "global_load_dwordx4 %12, %19, off\n\t"
      "global_load_dwordx4 %13, %19, off offset:1024\n\t"
      "global_load_dwordx4 %14, %19, off offset:2048\n\t"
      "global_load_dwordx4 %15, %19, off offset:3072\n\t"
      : "=&v"(B[16]), "=&v"(B[17]), "=&v"(B[18]), "=&v"(B[19]), "=&v"(B[20]),
        "=&v"(B[21]), "=&v"(B[22]), "=&v"(B[23]), "=&v"(B[24]), "=&v"(B[25]),
        "=&v"(B[26]), "=&v"(B[27]), "=&v"(B[28]), "=&v"(B[29]), "=&v"(B[30]),
        "=&v"(B[31])
      : "v"(wb + 16384), "v"(wb + 20480), "v"(wb + 24576), "v"(wb + 28672));

  f32x4 acc[4];
#pragma unroll
  for (int f = 0; f < 4; ++f) acc[f] = (f32x4){0.f, 0.f, 0.f, 0.f};

#pragma unroll
  for (int ks = 0; ks < 4; ++ks) {
    union { __hip_bfloat162 h[4]; bf16x8 v; } cu;
    cu.h[0] = __float22bfloat162_rn(make_float2(a[2 * ks][0], a[2 * ks][1]));
    cu.h[1] = __float22bfloat162_rn(make_float2(a[2 * ks][2], a[2 * ks][3]));
    cu.h[2] = __float22bfloat162_rn(make_float2(a[2 * ks + 1][0], a[2 * ks + 1][1]));
    cu.h[3] = __float22bfloat162_rn(make_float2(a[2 * ks + 1][2], a[2 * ks + 1][3]));
#pragma unroll
    for (int f = 0; f < 4; ++f)
      acc[f] = __builtin_amdgcn_mfma_f32_16x16x32_bf16(cu.v, B[ks * 4 + f], acc[f], 0, 0, 0);
  }

  WAITALL;  // B[16..31] ready

#pragma unroll
  for (int ks = 4; ks < 8; ++ks) {
    union { __hip_bfloat162 h[4]; bf16x8 v; } cu;
    cu.h[0] = __float22bfloat162_rn(make_float2(a[2 * ks][0], a[2 * ks][1]));
    cu.h[1] = __float22bfloat162_rn(make_float2(a[2 * ks][2], a[2 * ks][3]));
    cu.h[2] = __float22bfloat162_rn(make_float2(a[2 * ks + 1][0], a[2 * ks + 1][1]));
    cu.h[3] = __float22bfloat162_rn(make_float2(a[2 * ks + 1][2], a[2 * ks + 1][3]));
#pragma unroll
    for (int f = 0; f < 4; ++f)
      acc[f] = __builtin_amdgcn_mfma_f32_16x16x32_bf16(cu.v, B[ks * 4 + f], acc[f], 0, 0, 0);
  }

  const int orow0 = bblk * 64 + wv * 16 + half * 4;
#pragma unroll
  for (int f = 0; f < 4; ++f) {
#pragma unroll
    for (int rg = 0; rg < 4; ++rg) {
      int orow = orow0 + rg;
      if (orow < N) Hb[((size_t)g * N + orow) * HD + f * 16 + r16] = f2bf(acc[f][rg]);
    }
  }
}

// ---------------- GEMM2 bf16 K=64 (rows = 2N): asm-batched loads, no LDS -----
__global__ __launch_bounds__(256) void k_gemm2(const unsigned short* __restrict__ Xb,
                                               const unsigned short* __restrict__ Wfh,
                                               const unsigned short* __restrict__ Wfl,
                                               unsigned short* __restrict__ Hb, int M) {
  const int tid = threadIdx.x;
  const int row0 = blockIdx.x * 64;
  const int lane = tid & 63;
  const int wv = tid >> 6;
  const int r16 = lane & 15;
  const int half = lane >> 4;
  const int row = row0 + wv * 16 + r16;
  const int rowc = min(row, M - 1);

  unsigned long long xa =
      (unsigned long long)(const void*)(Xb + (size_t)rowc * 64 + half * 8);
  const unsigned long long bh = (unsigned long long)(const void*)Wfh + lane * 16;
  const unsigned long long bl = (unsigned long long)(const void*)Wfl + lane * 16;
  u32x4 A0, A1;
  bf16x8 BH[8], BL[8];
  asm volatile(
      "global_load_dwordx4 %0, %18, off\n\t"
      "global_load_dwordx4 %1, %18, off offset:64\n\t"
      "global_load_dwordx4 %2, %19, off\n\t"
      "global_load_dwordx4 %3, %19, off offset:1024\n\t"
      "global_load_dwordx4 %4, %19, off offset:2048\n\t"
      "global_load_dwordx4 %5, %19, off offset:3072\n\t"
      "global_load_dwordx4 %6, %20, off\n\t"
      "global_load_dwordx4 %7, %20, off offset:1024\n\t"
      "global_load_dwordx4 %8, %20, off offset:2048\n\t"
      "global_load_dwordx4 %9, %20, off offset:3072\n\t"
      "global_load_dwordx4 %10, %21, off\n\t"
      "global_load_dwordx4 %11, %21, off offset:1024\n\t"
      "global_load_dwordx4 %12, %21, off offset:2048\n\t"
      "global_load_dwordx4 %13, %21, off offset:3072\n\t"
      "global_load_dwordx4 %14, %22, off\n\t"
      "global_load_dwordx4 %15, %22, off offset:1024\n\t"
      "global_load_dwordx4 %16, %22, off offset:2048\n\t"
      "global_load_dwordx4 %17, %22, off offset:3072\n\t"
      : "=&v"(A0), "=&v"(A1), "=&v"(BH[0]), "=&v"(BH[1]), "=&v"(BH[2]),
        "=&v"(BH[3]), "=&v"(BH[4]), "=&v"(BH[5]), "=&v"(BH[6]), "=&v"(BH[7]),
        "=&v"(BL[0]), "=&v"(BL[1]), "=&v"(BL[2]), "=&v"(BL[3]), "=&v"(BL[4]),
        "=&v"(BL[5]), "=&v"(BL[6]), "=&v"(BL[7])
      : "v"(xa), "v"(bh), "v"(bh + 4096), "v"(bl), "v"(bl + 4096));

  WAITALL;

  f32x4 acc[4];
#pragma unroll
  for (int f = 0; f < 4; ++f) acc[f] = (f32x4){0.f, 0.f, 0.f, 0.f};

  union { u32x4 u; bf16x8 v; } a0u, a1u;
  a0u.u = A0;
  a1u.u = A1;
#pragma unroll
  for (int f = 0; f < 4; ++f) {
    acc[f] = __builtin_amdgcn_mfma_f32_16x16x32_bf16(a0u.v, BH[f], acc[f], 0, 0, 0);
    acc[f] = __builtin_amdgcn_mfma_f32_16x16x32_bf16(a0u.v, BL[f], acc[f], 0, 0, 0);
    acc[f] = __builtin_amdgcn_mfma_f32_16x16x32_bf16(a1u.v, BH[4 + f], acc[f], 0, 0, 0);
    acc[f] = __builtin_amdgcn_mfma_f32_16x16x32_bf16(a1u.v, BL[4 + f], acc[f], 0, 0, 0);
  }

  const int orow0 = row0 + wv * 16 + half * 4;
#pragma unroll
  for (int f = 0; f < 4; ++f) {
#pragma unroll
    for (int rg = 0; rg < 4; ++rg) {
      int orow = orow0 + rg;
      if (orow < M) Hb[(size_t)orow * HD + f * 16 + r16] = f2bf(acc[f][rg]);
    }
  }
}

// ---------------- Aggregation (both graphs): 16 lanes/node, uint2 gathers ----
template <int OUTBF16>
__global__ __launch_bounds__(256) void k_agg(const unsigned short* __restrict__ Hb,
                                             const int* __restrict__ recs,
                                             const int* __restrict__ row_start,
                                             const float* __restrict__ dinv,
                                             const float* __restrict__ bias,
                                             void* __restrict__ outv, int N, int E,
                                             int relu) {
  const int t = threadIdx.x;
  const int nglob = (blockIdx.x * blockDim.x + t) >> 4;
  const int lane16 = t & 15;
  if (nglob >= 2 * N) return;
  const int g = nglob >= N;
  const int node = nglob - g * N;
  const int* __restrict__ rsg = row_start + (size_t)g * (N + 1);
  const int* __restrict__ R = recs + (size_t)g * E;
  const float* __restrict__ dig = dinv + (size_t)g * N;
  const unsigned short* __restrict__ Hbg = Hb + (size_t)g * N * HD;

  const int c0 = lane16 * 4;
  float di = dig[node];
  float a0, a1, a2, a3;
  {
    uint2 h = *(const uint2*)&Hbg[(size_t)node * HD + c0];
    float dd = di * di;
    a0 = bf2f((unsigned short)(h.x & 0xffff)) * dd;
    a1 = bf2f((unsigned short)(h.x >> 16)) * dd;
    a2 = bf2f((unsigned short)(h.y & 0xffff)) * dd;
    a3 = bf2f((unsigned short)(h.y >> 16)) * dd;
  }
  const int beg = rsg[node], end = rsg[node + 1];
  int e = beg;
  for (; e + 8 <= end; e += 8) {
    int s[8];
    uint2 gg[8];
    float n[8];
#pragma unroll
    for (int j = 0; j < 8; ++j) s[j] = R[e + j];
#pragma unroll
    for (int j = 0; j < 8; ++j) {
      gg[j] = *(const uint2*)&Hbg[(size_t)s[j] * HD + c0];
      n[j] = dig[s[j]];
    }
#pragma unroll
    for (int j = 0; j < 8; ++j) {
      float nn = n[j] * di;
      a0 = fmaf(bf2f((unsigned short)(gg[j].x & 0xffff)), nn, a0);
      a1 = fmaf(bf2f((unsigned short)(gg[j].x >> 16)), nn, a1);
      a2 = fmaf(bf2f((unsigned short)(gg[j].y & 0xffff)), nn, a2);
      a3 = fmaf(bf2f((unsigned short)(gg[j].y >> 16)), nn, a3);
    }
  }
  for (; e < end; ++e) {
    int s = R[e];
    uint2 gg = *(const uint2*)&Hbg[(size_t)s * HD + c0];
    float nn = dig[s] * di;
    a0 = fmaf(bf2f((unsigned short)(gg.x & 0xffff)), nn, a0);
    a1 = fmaf(bf2f((unsigned short)(gg.x >> 16)), nn, a1);
    a2 = fmaf(bf2f((unsigned short)(gg.y & 0xffff)), nn, a2);
    a3 = fmaf(bf2f((unsigned short)(gg.y >> 16)), nn, a3);
  }
  float4 bv = *(const float4*)&bias[c0];
  a0 += bv.x; a1 += bv.y; a2 += bv.z; a3 += bv.w;
  if (relu) {
    a0 = fmaxf(a0, 0.f); a1 = fmaxf(a1, 0.f);
    a2 = fmaxf(a2, 0.f); a3 = fmaxf(a3, 0.f);
  }
  if (OUTBF16) {
    uint2 o;
    o.x = ((unsigned)f2bf(a1) << 16) | f2bf(a0);
    o.y = ((unsigned)f2bf(a3) << 16) | f2bf(a2);
    *(uint2*)&((unsigned short*)outv)[(size_t)nglob * HD + c0] = o;
  } else {
    *(float4*)&((float*)outv)[(size_t)nglob * HD + c0] = make_float4(a0, a1, a2, a3);
  }
}

// ---------------- zscore (both graphs) ----------------

__global__ void k_colstats(const float* __restrict__ H, float* __restrict__ stats, int N,
                           int gridPer) {
  __shared__ float ss[256], sq[256];
  const int g = blockIdx.x / gridPer;
  const int blk = blockIdx.x % gridPer;
  const float* __restrict__ Hg = H + (size_t)g * N * HD;
  float* __restrict__ st = stats + g * 128;
  int t = threadIdx.x;
  int col = t & 63, grp = t >> 6;
  float s = 0.f, q = 0.f;
  for (int row = blk * 4 + grp; row < N; row += gridPer * 4) {
    float v = Hg[(size_t)row * HD + col];
    s += v;
    q += v * v;
  }
  ss[t] = s;
  sq[t] = q;
  __syncthreads();
  if (t < 64) {
    s = ss[t] + ss[t + 64] + ss[t + 128] + ss[t + 192];
    q = sq[t] + sq[t + 64] + sq[t + 128] + sq[t + 192];
    atomicAdd(&st[t], s);
    atomicAdd(&st[64 + t], q);
  }
}

__global__ void k_normalize(float* __restrict__ H, const float* __restrict__ stats, int N) {
  int i = blockIdx.x * blockDim.x + threadIdx.x;
  int total = 2 * N * HD;
  if (i >= total) return;
  int col = i & 63;
  const float* st = stats + (i >= N * HD ? 128 : 0);
  float sum = st[col], sumsq = st[64 + col];
  float mean = sum / (float)N;
  float var = (sumsq - sum * sum / (float)N) / (float)(N - 1);
  float r = rsqrtf(var);
  H[i] = (H[i] - mean) * r;
}

// ---------------- launch ----------------

extern "C" void kernel_launch(void* const* d_in, const int* in_sizes, int n_in,
                              void* d_out, int out_size, void* d_ws, size_t ws_size,
                              hipStream_t stream) {
  const int IN_DIM = 256;
  const float* X1 = (const float*)d_in[0];
  const float* X2 = (const float*)d_in[2];
  const int* EI1 = (const int*)d_in[1];
  const int* EI2 = (const int*)d_in[3];
  const float* W1 = (const float*)d_in[4];
  const float* b1 = (const float*)d_in[5];
  const float* W2 = (const float*)d_in[6];
  const float* b2 = (const float*)d_in[7];
  const int N = in_sizes[0] / IN_DIM;
  const int E = in_sizes[1] / 2;
  const int NB = (N + (1 << BKT_SHIFT) - 1) >> BKT_SHIFT;  // 98
  const int NBLK = (E + CH - 1) / CH;                      // 196

  char* ws = (char*)d_ws;
  size_t off = 0;
  auto carve = [&](size_t bytes) -> char* {
    char* p = ws + off;
    off += (bytes + 255) & ~(size_t)255;
    return p;
  };
  unsigned short* Hb = (unsigned short*)carve((size_t)2 * N * HD * 2);  // both graphs
  int* tmp = (int*)carve((size_t)2 * NBLK * CH * 4);
  int* recs = (int*)carve((size_t)2 * E * 4);
  char* zero_base = carve(256 * 4);  // stats[2][128]
  float* stats = (float*)zero_base;
  int* row_start = (int*)carve((size_t)2 * (N + 1) * 4);
  float* dinv = (float*)carve((size_t)2 * N * 4);
  int* bucket_base = (int*)carve((size_t)2 * (NB + 1) * 4);
  int* counts = (int*)carve((size_t)2 * NB * NBLK * 4);
  int* offsets = (int*)carve((size_t)2 * NB * NBLK * 4);
  unsigned short* Wf1 = (unsigned short*)carve(256 * 64 * 2);
  unsigned short* Wf2hi = (unsigned short*)carve(64 * 64 * 2);
  unsigned short* Wf2lo = (unsigned short*)carve(64 * 64 * 2);
  unsigned short* bufAgg = (unsigned short*)d_out;  // alias: dead before agg2 writes
  (void)ws_size; (void)n_in; (void)out_size;

  const int T = 256;
  const int gPer1 = (N + 63) / 64;        // 64-row blocks, per graph
  const int gG2 = (2 * N + 63) / 64;      // gemm2 over 2N rows
  const int gAgg = (2 * N * 16 + T - 1) / T;
  const int gCS = 512;
  const int gElem = (2 * N * HD + T - 1) / T;
  const int gWp = (256 * 64 + 64 * 64 + T - 1) / T;  // 80

  (void)hipMemsetAsync(zero_base, 0, 256 * 4, stream);
  k_wprep<<<gWp, T, 0, stream>>>(W1, W2, Wf1, Wf2hi, Wf2lo);
  k_bin1<<<2 * NBLK, T, 0, stream>>>(EI1, EI1 + E, EI2, EI2 + E, tmp, counts, offsets,
                                     NB, NBLK, E);
  k_bscan<<<2, 128, 0, stream>>>(counts, bucket_base, row_start, NB, NBLK, N, E);
  k_bin2m<<<2 * NB, 1024, 0, stream>>>(tmp, counts, offsets, bucket_base, row_start,
                                       dinv, recs, N, NB, NBLK, E);

  // layer 1 (both graphs): h = relu(agg(x @ W1) + b1) -> bufAgg (bf16, in d_out)
  k_gemm1<<<2 * gPer1, T, 0, stream>>>(X1, X2, Wf1, Hb, N, gPer1);
  k_agg<1><<<gAgg, T, 0, stream>>>(Hb, recs, row_start, dinv, b1, bufAgg, N, E, 1);
  // layer 2 (both graphs as one 2N-row GEMM): h2 = agg(h1 @ W2) + b2 -> d_out f32
  k_gemm2<<<gG2, T, 0, stream>>>(bufAgg, Wf2hi, Wf2lo, Hb, 2 * N);
  k_agg<0><<<gAgg, T, 0, stream>>>(Hb, recs, row_start, dinv, b2, d_out, N, E, 0);

  // zscore in place on d_out (per graph)
  k_colstats<<<2 * gCS, T, 0, stream>>>((float*)d_out, stats, N, gCS);
  k_normalize<<<gElem, T, 0, stream>>>((float*)d_out, stats, N);
}

// Round 21
// 363.992 us; speedup vs baseline: 1.0150x; 1.0150x over previous
//
#include <hip/hip_runtime.h>
#include <hip/hip_bf16.h>

#define HD 64        // hidden == out dim
#define CH 8192      // edges per bin1 block
#define BKT_SHIFT 10 // 1024 nodes per bucket
#define SRC_BITS 17  // N=100000 < 2^17 -> {dstlocal:10 | src:17} fits in 27 bits
#define MAXBLK 256   // >= NBLK = ceil(E/CH) = 196

typedef __attribute__((ext_vector_type(8))) short bf16x8;
typedef __attribute__((ext_vector_type(4))) float f32x4;
typedef __attribute__((ext_vector_type(4))) unsigned int u32x4;

#define WAITALL do { asm volatile("s_waitcnt vmcnt(0)" ::: "memory"); \
                     __builtin_amdgcn_sched_barrier(0); } while (0)

__device__ inline unsigned short f2bf(float x) {
  unsigned u = __float_as_uint(x);
  unsigned r = u + 0x7FFF + ((u >> 16) & 1);
  return (unsigned short)(r >> 16);
}
__device__ inline float bf2f(unsigned short h) {
  return __uint_as_float(((unsigned)h) << 16);
}

// ---------------- W fragment prep: lane-indexed MFMA B-frags in global -------
// (separate kernel: k_front's gemm branch READS Wf1 -> must be ordered before)
__global__ __launch_bounds__(256) void k_wprep(const float* __restrict__ W1,
                                               const float* __restrict__ W2,
                                               unsigned short* __restrict__ Wf1,
                                               unsigned short* __restrict__ Wf2hi,
                                               unsigned short* __restrict__ Wf2lo) {
  int idx = blockIdx.x * blockDim.x + threadIdx.x;
  if (idx < 256 * 64) {
    int k = idx >> 6, c = idx & 63;
    float w = W1[idx];
    int ks = k >> 5, r = k & 31, h2 = r >> 3, j = r & 7;
    int f = c >> 4, r16c = c & 15;
    int pos = (((ks * 4 + f) * 64) + h2 * 16 + r16c) * 8 + j;
    Wf1[pos] = f2bf(w);
  } else if (idx < 256 * 64 + 64 * 64) {
    int i2 = idx - 256 * 64;
    int k = i2 >> 6, c = i2 & 63;
    float w = W2[i2];
    int ks = k >> 5, r = k & 31, h2 = r >> 3, j = r & 7;
    int f = c >> 4, r16c = c & 15;
    int pos = (((ks * 4 + f) * 64) + h2 * 16 + r16c) * 8 + j;
    unsigned short hi = f2bf(w);
    Wf2hi[pos] = hi;
    Wf2lo[pos] = f2bf(w - bf2f(hi));
  }
}

// ---------------- FRONT: gemm1 (asm-batched, no LDS) || bin1 (LDS bucket sort)
// gemm1 and the edge-binning pass are data-independent; merging them into one
// launch co-schedules their waves (bin1's ~25us hides under gemm1's ~80us
// latency-bound phase).
__global__ __launch_bounds__(256) void k_front(
    const float* __restrict__ X0, const float* __restrict__ X1,
    const unsigned short* __restrict__ Wf1, unsigned short* __restrict__ Hb,
    int N, int gPer,
    const int* __restrict__ srcA, const int* __restrict__ dstA,
    const int* __restrict__ srcB, const int* __restrict__ dstB,
    int* __restrict__ tmp, int* __restrict__ counts, int* __restrict__ offsets,
    int NB, int NBLK, int E) {
  __shared__ int hist[128];
  __shared__ int pref[128];
  __shared__ int lofs[128];
  __shared__ int stage[CH];  // 32 KB (bin branch only)
  const int tid = threadIdx.x;
  const int bid = blockIdx.x;
  const int nGemm = 2 * gPer;

  if (bid < nGemm) {
    // ---------------- gemm1 branch ----------------
    const int g = bid / gPer;
    const int bblk = bid % gPer;
    const float* __restrict__ Xv = g ? X1 : X0;
    const int lane = tid & 63;
    const int wv = tid >> 6;
    const int r16 = lane & 15;
    const int half = lane >> 4;
    const int row = bblk * 64 + wv * 16 + r16;
    const int rowc = min(row, N - 1);

    unsigned long long xa =
        (unsigned long long)(const void*)(Xv + (size_t)rowc * 256 + half * 8);
    f32x4 a[16];
    asm volatile(
        "global_load_dwordx4 %0, %16, off\n\t"
        "global_load_dwordx4 %1, %16, off offset:16\n\t"
        "global_load_dwordx4 %2, %16, off offset:128\n\t"
        "global_load_dwordx4 %3, %16, off offset:144\n\t"
        "global_load_dwordx4 %4, %16, off offset:256\n\t"
        "global_load_dwordx4 %5, %16, off offset:272\n\t"
        "global_load_dwordx4 %6, %16, off offset:384\n\t"
        "global_load_dwordx4 %7, %16, off offset:400\n\t"
        "global_load_dwordx4 %8, %16, off offset:512\n\t"
        "global_load_dwordx4 %9, %16, off offset:528\n\t"
        "global_load_dwordx4 %10, %16, off offset:640\n\t"
        "global_load_dwordx4 %11, %16, off offset:656\n\t"
        "global_load_dwordx4 %12, %16, off offset:768\n\t"
        "global_load_dwordx4 %13, %16, off offset:784\n\t"
        "global_load_dwordx4 %14, %16, off offset:896\n\t"
        "global_load_dwordx4 %15, %16, off offset:912\n\t"
        : "=&v"(a[0]), "=&v"(a[1]), "=&v"(a[2]), "=&v"(a[3]), "=&v"(a[4]),
          "=&v"(a[5]), "=&v"(a[6]), "=&v"(a[7]), "=&v"(a[8]), "=&v"(a[9]),
          "=&v"(a[10]), "=&v"(a[11]), "=&v"(a[12]), "=&v"(a[13]), "=&v"(a[14]),
          "=&v"(a[15])
        : "v"(xa));

    const unsigned long long wb = (unsigned long long)(const void*)Wf1 + lane * 16;
    bf16x8 B[32];
    asm volatile(
        "global_load_dwordx4 %0, %16, off\n\t"
        "global_load_dwordx4 %1, %16, off offset:1024\n\t"
        "global_load_dwordx4 %2, %16, off offset:2048\n\t"
        "global_load_dwordx4 %3, %16, off offset:3072\n\t"
        "global_load_dwordx4 %4, %17, off\n\t"
        "global_load_dwordx4 %5, %17, off offset:1024\n\t"
        "global_load_dwordx4 %6, %17, off offset:2048\n\t"
        "global_load_dwordx4 %7, %17, off offset:3072\n\t"
        "global_load_dwordx4 %8, %18, off\n\t"
        "global_load_dwordx4 %9, %18, off offset:1024\n\t"
        "global_load_dwordx4 %10, %18, off offset:2048\n\t"
        "global_load_dwordx4 %11, %18, off offset:3072\n\t"
        "global_load_dwordx4 %12, %19, off\n\t"
        "global_load_dwordx4 %13, %19, off offset:1024\n\t"
        "global_load_dwordx4 %14, %19, off offset:2048\n\t"
        "global_load_dwordx4 %15, %19, off offset:3072\n\t"
        : "=&v"(B[0]), "=&v"(B[1]), "=&v"(B[2]), "=&v"(B[3]), "=&v"(B[4]),
          "=&v"(B[5]), "=&v"(B[6]), "=&v"(B[7]), "=&v"(B[8]), "=&v"(B[9]),
          "=&v"(B[10]), "=&v"(B[11]), "=&v"(B[12]), "=&v"(B[13]), "=&v"(B[14]),
          "=&v"(B[15])
        : "v"(wb), "v"(wb + 4096), "v"(wb + 8192), "v"(wb + 12288));

    WAITALL;

    asm volatile(
        "global_load_dwordx4 %0, %16, off\n\t"
        "global_load_dwordx4 %1, %16, off offset:1024\n\t"
        "global_load_dwordx4 %2, %16, off offset:2048\n\t"
        "global_load_dwordx4 %3, %16, off offset:3072\n\t"
        "global_load_dwordx4 %4, %17, off\n\t"
        "global_load_dwordx4 %5, %17, off offset:1024\n\t"
        "global_load_dwordx4 %6, %17, off offset:2048\n\t"
        "global_load_dwordx4 %7, %17, off offset:3072\n\t"
        "global_load_dwordx4 %8, %18, off\n\t"
        "global_load_dwordx4 %9, %18, off offset:1024\n\t"
        "global_load_dwordx4 %10, %18, off offset:2048\n\t"
        "global_load_dwordx4 %11, %18, off offset:3072\n\t"
        "global_load_dwordx4 %12, %19, off\n\t"
        "global_load_dwordx4 %13, %19, off offset:1024\n\t"
        "global_load_dwordx4 %14, %19, off offset:2048\n\t"
        "global_load_dwordx4 %15, %19, off offset:3072\n\t"
        : "=&v"(B[16]), "=&v"(B[17]), "=&v"(B[18]), "=&v"(B[19]), "=&v"(B[20]),
          "=&v"(B[21]), "=&v"(B[22]), "=&v"(B[23]), "=&v"(B[24]), "=&v"(B[25]),
          "=&v"(B[26]), "=&v"(B[27]), "=&v"(B[28]), "=&v"(B[29]), "=&v"(B[30]),
          "=&v"(B[31])
        : "v"(wb + 16384), "v"(wb + 20480), "v"(wb + 24576), "v"(wb + 28672));

    f32x4 acc[4];
#pragma unroll
    for (int f = 0; f < 4; ++f) acc[f] = (f32x4){0.f, 0.f, 0.f, 0.f};

#pragma unroll
    for (int ks = 0; ks < 4; ++ks) {
      union { __hip_bfloat162 h[4]; bf16x8 v; } cu;
      cu.h[0] = __float22bfloat162_rn(make_float2(a[2 * ks][0], a[2 * ks][1]));
      cu.h[1] = __float22bfloat162_rn(make_float2(a[2 * ks][2], a[2 * ks][3]));
      cu.h[2] = __float22bfloat162_rn(make_float2(a[2 * ks + 1][0], a[2 * ks + 1][1]));
      cu.h[3] = __float22bfloat162_rn(make_float2(a[2 * ks + 1][2], a[2 * ks + 1][3]));
#pragma unroll
      for (int f = 0; f < 4; ++f)
        acc[f] = __builtin_amdgcn_mfma_f32_16x16x32_bf16(cu.v, B[ks * 4 + f], acc[f], 0, 0, 0);
    }

    WAITALL;

#pragma unroll
    for (int ks = 4; ks < 8; ++ks) {
      union { __hip_bfloat162 h[4]; bf16x8 v; } cu;
      cu.h[0] = __float22bfloat162_rn(make_float2(a[2 * ks][0], a[2 * ks][1]));
      cu.h[1] = __float22bfloat162_rn(make_float2(a[2 * ks][2], a[2 * ks][3]));
      cu.h[2] = __float22bfloat162_rn(make_float2(a[2 * ks + 1][0], a[2 * ks + 1][1]));
      cu.h[3] = __float22bfloat162_rn(make_float2(a[2 * ks + 1][2], a[2 * ks + 1][3]));
#pragma unroll
      for (int f = 0; f < 4; ++f)
        acc[f] = __builtin_amdgcn_mfma_f32_16x16x32_bf16(cu.v, B[ks * 4 + f], acc[f], 0, 0, 0);
    }

    const int orow0 = bblk * 64 + wv * 16 + half * 4;
#pragma unroll
    for (int f = 0; f < 4; ++f) {
#pragma unroll
      for (int rg = 0; rg < 4; ++rg) {
        int orow = orow0 + rg;
        if (orow < N) Hb[((size_t)g * N + orow) * HD + f * 16 + r16] = f2bf(acc[f][rg]);
      }
    }
    return;
  }

  // ---------------- bin1 branch ----------------
  const int blk2 = bid - nGemm;
  const int g = blk2 / NBLK;
  const int blk = blk2 % NBLK;
  const int* __restrict__ src = g ? srcB : srcA;
  const int* __restrict__ dst = g ? dstB : dstA;
  int* __restrict__ tmpg = tmp + (size_t)g * NBLK * CH;
  int* __restrict__ cntg = counts + (size_t)g * NB * NBLK;
  int* __restrict__ offg = offsets + (size_t)g * NB * NBLK;
  const int e0 = blk * CH;
  const int len = min(CH, E - e0);
  const int t = tid;

  for (int i = t; i < 128; i += 256) hist[i] = 0;
  __syncthreads();
  int dreg[CH / 256];
#pragma unroll
  for (int it = 0; it < CH / 256; ++it) {
    int i = t + it * 256;
    if (i < len) {
      int d = dst[e0 + i];
      dreg[it] = d;
      atomicAdd(&hist[d >> BKT_SHIFT], 1);
    }
  }
  __syncthreads();
  if (t < 128) pref[t] = hist[t];
  __syncthreads();
  for (int off = 1; off < 128; off <<= 1) {
    int v = 0;
    if (t < 128 && t >= off) v = pref[t - off];
    __syncthreads();
    if (t < 128) pref[t] += v;
    __syncthreads();
  }
  if (t < NB) {
    int ex = pref[t] - hist[t];
    lofs[t] = ex;
    cntg[t * NBLK + blk] = hist[t];   // [bucket][block]
    offg[t * NBLK + blk] = ex;
  }
  __syncthreads();
#pragma unroll
  for (int it = 0; it < CH / 256; ++it) {
    int i = t + it * 256;
    if (i < len) {
      int d = dreg[it], s = src[e0 + i];
      int slot = atomicAdd(&lofs[d >> BKT_SHIFT], 1);
      stage[slot] = ((d & ((1 << BKT_SHIFT) - 1)) << SRC_BITS) | s;
    }
  }
  __syncthreads();
  int nv = len >> 2;
  for (int i = t; i < nv; i += 256) ((int4*)(tmpg + e0))[i] = ((const int4*)stage)[i];
  for (int i = (nv << 2) + t; i < len; i += 256) tmpg[e0 + i] = stage[i];
}

// ---------------- bucket totals + exclusive scan (one block per graph) -------
__global__ __launch_bounds__(128) void k_bscan(const int* __restrict__ counts,
                                               int* __restrict__ bucket_base,
                                               int* __restrict__ row_start,
                                               int NB, int NBLK, int N, int E) {
  __shared__ int sh[128];
  const int g = blockIdx.x;
  const int* __restrict__ cntg = counts + (size_t)g * NB * NBLK;
  int* __restrict__ bbg = bucket_base + g * (NB + 1);
  int* __restrict__ rsg = row_start + (size_t)g * (N + 1);
  int t = threadIdx.x;
  int v = 0;
  if (t < NB) {
    const int* p = cntg + t * NBLK;
    for (int i = 0; i < NBLK; ++i) v += p[i];
  }
  sh[t] = v;
  __syncthreads();
  for (int off = 1; off < 128; off <<= 1) {
    int x = (t >= off) ? sh[t - off] : 0;
    __syncthreads();
    sh[t] += x;
    __syncthreads();
  }
  if (t < NB) bbg[t] = sh[t] - v;  // exclusive
  if (t == 0) {
    bbg[NB] = E;
    rsg[N] = E;
  }
}

// ---------------- merged bin2 (both graphs): hist + scan + place -------------
__global__ __launch_bounds__(1024) void k_bin2m(const int* __restrict__ tmp,
                                                const int* __restrict__ counts,
                                                const int* __restrict__ offsets,
                                                const int* __restrict__ bucket_base,
                                                int* __restrict__ row_start,
                                                float* __restrict__ dinv,
                                                int* __restrict__ recs, int N, int NB,
                                                int NBLK, int E) {
  __shared__ int h[1 << BKT_SHIFT];
  __shared__ int lcur[1 << BKT_SHIFT];
  __shared__ int scnt[MAXBLK], soff[MAXBLK];
  const int g = blockIdx.x / NB;
  const int b = blockIdx.x % NB;
  const int* __restrict__ tmpg = tmp + (size_t)g * NBLK * CH;
  const int* __restrict__ cntg = counts + (size_t)g * NB * NBLK;
  const int* __restrict__ offg = offsets + (size_t)g * NB * NBLK;
  const int* __restrict__ bbg = bucket_base + g * (NB + 1);
  int* __restrict__ rsg = row_start + (size_t)g * (N + 1);
  float* __restrict__ dig = dinv + (size_t)g * N;
  int* __restrict__ recg = recs + (size_t)g * E;
  const int t = threadIdx.x;
  const int node0 = b << BKT_SHIFT;
  const int lane = t & 63, w = t >> 6;

  h[t] = 0;
  for (int i = t; i < NBLK; i += 1024) {
    scnt[i] = cntg[b * NBLK + i];
    soff[i] = offg[b * NBLK + i];
  }
  __syncthreads();
  for (int blk = w; blk < NBLK; blk += 16) {
    int cnt = scnt[blk];
    const int* p = tmpg + blk * CH + soff[blk];
    for (int j = lane; j < cnt; j += 64) atomicAdd(&h[p[j] >> SRC_BITS], 1);
  }
  __syncthreads();
  int deg = h[t];
  __syncthreads();
  for (int off = 1; off < 1024; off <<= 1) {
    int x = (t >= off) ? h[t - off] : 0;
    __syncthreads();
    h[t] += x;
    __syncthreads();
  }
  int base = bbg[b] + h[t] - deg;
  lcur[t] = base;
  int n = node0 + t;
  if (n < N) {
    rsg[n] = base;
    dig[n] = rsqrtf((float)deg + 1.0f);
  }
  __syncthreads();
  for (int blk = w; blk < NBLK; blk += 16) {
    int cnt = scnt[blk];
    const int* p = tmpg + blk * CH + soff[blk];
    for (int j = lane; j < cnt; j += 64) {
      int rec = p[j];
      int d = rec >> SRC_BITS;
      int s = rec & ((1 << SRC_BITS) - 1);
      int slot = atomicAdd(&lcur[d], 1);
      recg[slot] = s;
    }
  }
}

// ---------------- GEMM2 bf16 K=64 (rows = 2N): asm-batched loads, no LDS -----
__global__ __launch_bounds__(256) void k_gemm2(const unsigned short* __restrict__ Xb,
                                               const unsigned short* __restrict__ Wfh,
                                               const unsigned short* __restrict__ Wfl,
                                               unsigned short* __restrict__ Hb, int M) {
  const int tid = threadIdx.x;
  const int row0 = blockIdx.x * 64;
  const int lane = tid & 63;
  const int wv = tid >> 6;
  const int r16 = lane & 15;
  const int half = lane >> 4;
  const int row = row0 + wv * 16 + r16;
  const int rowc = min(row, M - 1);

  unsigned long long xa =
      (unsigned long long)(const void*)(Xb + (size_t)rowc * 64 + half * 8);
  const unsigned long long bh = (unsigned long long)(const void*)Wfh + lane * 16;
  const unsigned long long bl = (unsigned long long)(const void*)Wfl + lane * 16;
  u32x4 A0, A1;
  bf16x8 BH[8], BL[8];
  asm volatile(
      "global_load_dwordx4 %0, %18, off\n\t"
      "global_load_dwordx4 %1, %18, off offset:64\n\t"
      "global_load_dwordx4 %2, %19, off\n\t"
      "global_load_dwordx4 %3, %19, off offset:1024\n\t"
      "global_load_dwordx4 %4, %19, off offset:2048\n\t"
      "global_load_dwordx4 %5, %19, off offset:3072\n\t"
      "global_load_dwordx4 %6, %20, off\n\t"
      "global_load_dwordx4 %7, %20, off offset:1024\n\t"
      "global_load_dwordx4 %8, %20, off offset:2048\n\t"
      "global_load_dwordx4 %9, %20, off offset:3072\n\t"
      "global_load_dwordx4 %10, %21, off\n\t"
      "global_load_dwordx4 %11, %21, off offset:1024\n\t"
      "global_load_dwordx4 %12, %21, off offset:2048\n\t"
      "global_load_dwordx4 %13, %21, off offset:3072\n\t"
      "global_load_dwordx4 %14, %22, off\n\t"
      "global_load_dwordx4 %15, %22, off offset:1024\n\t"
      "global_load_dwordx4 %16, %22, off offset:2048\n\t"
      "global_load_dwordx4 %17, %22, off offset:3072\n\t"
      : "=&v"(A0), "=&v"(A1), "=&v"(BH[0]), "=&v"(BH[1]), "=&v"(BH[2]),
        "=&v"(BH[3]), "=&v"(BH[4]), "=&v"(BH[5]), "=&v"(BH[6]), "=&v"(BH[7]),
        "=&v"(BL[0]), "=&v"(BL[1]), "=&v"(BL[2]), "=&v"(BL[3]), "=&v"(BL[4]),
        "=&v"(BL[5]), "=&v"(BL[6]), "=&v"(BL[7])
      : "v"(xa), "v"(bh), "v"(bh + 4096), "v"(bl), "v"(bl + 4096));

  WAITALL;

  f32x4 acc[4];
#pragma unroll
  for (int f = 0; f < 4; ++f) acc[f] = (f32x4){0.f, 0.f, 0.f, 0.f};

  union { u32x4 u; bf16x8 v; } a0u, a1u;
  a0u.u = A0;
  a1u.u = A1;
#pragma unroll
  for (int f = 0; f < 4; ++f) {
    acc[f] = __builtin_amdgcn_mfma_f32_16x16x32_bf16(a0u.v, BH[f], acc[f], 0, 0, 0);
    acc[f] = __builtin_amdgcn_mfma_f32_16x16x32_bf16(a0u.v, BL[f], acc[f], 0, 0, 0);
    acc[f] = __builtin_amdgcn_mfma_f32_16x16x32_bf16(a1u.v, BH[4 + f], acc[f], 0, 0, 0);
    acc[f] = __builtin_amdgcn_mfma_f32_16x16x32_bf16(a1u.v, BL[4 + f], acc[f], 0, 0, 0);
  }

  const int orow0 = row0 + wv * 16 + half * 4;
#pragma unroll
  for (int f = 0; f < 4; ++f) {
#pragma unroll
    for (int rg = 0; rg < 4; ++rg) {
      int orow = orow0 + rg;
      if (orow < M) Hb[(size_t)orow * HD + f * 16 + r16] = f2bf(acc[f][rg]);
    }
  }
}

// ---------------- Aggregation (both graphs): 16 lanes/node, uint2 gathers ----
template <int OUTBF16>
__global__ __launch_bounds__(256) void k_agg(const unsigned short* __restrict__ Hb,
                                             const int* __restrict__ recs,
                                             const int* __restrict__ row_start,
                                             const float* __restrict__ dinv,
                                             const float* __restrict__ bias,
                                             void* __restrict__ outv, int N, int E,
                                             int relu) {
  const int t = threadIdx.x;
  const int nglob = (blockIdx.x * blockDim.x + t) >> 4;
  const int lane16 = t & 15;
  if (nglob >= 2 * N) return;
  const int g = nglob >= N;
  const int node = nglob - g * N;
  const int* __restrict__ rsg = row_start + (size_t)g * (N + 1);
  const int* __restrict__ R = recs + (size_t)g * E;
  const float* __restrict__ dig = dinv + (size_t)g * N;
  const unsigned short* __restrict__ Hbg = Hb + (size_t)g * N * HD;

  const int c0 = lane16 * 4;
  float di = dig[node];
  float a0, a1, a2, a3;
  {
    uint2 h = *(const uint2*)&Hbg[(size_t)node * HD + c0];
    float dd = di * di;
    a0 = bf2f((unsigned short)(h.x & 0xffff)) * dd;
    a1 = bf2f((unsigned short)(h.x >> 16)) * dd;
    a2 = bf2f((unsigned short)(h.y & 0xffff)) * dd;
    a3 = bf2f((unsigned short)(h.y >> 16)) * dd;
  }
  const int beg = rsg[node], end = rsg[node + 1];
  int e = beg;
  for (; e + 8 <= end; e += 8) {
    int s[8];
    uint2 gg[8];
    float n[8];
#pragma unroll
    for (int j = 0; j < 8; ++j) s[j] = R[e + j];
#pragma unroll
    for (int j = 0; j < 8; ++j) {
      gg[j] = *(const uint2*)&Hbg[(size_t)s[j] * HD + c0];
      n[j] = dig[s[j]];
    }
#pragma unroll
    for (int j = 0; j < 8; ++j) {
      float nn = n[j] * di;
      a0 = fmaf(bf2f((unsigned short)(gg[j].x & 0xffff)), nn, a0);
      a1 = fmaf(bf2f((unsigned short)(gg[j].x >> 16)), nn, a1);
      a2 = fmaf(bf2f((unsigned short)(gg[j].y & 0xffff)), nn, a2);
      a3 = fmaf(bf2f((unsigned short)(gg[j].y >> 16)), nn, a3);
    }
  }
  for (; e < end; ++e) {
    int s = R[e];
    uint2 gg = *(const uint2*)&Hbg[(size_t)s * HD + c0];
    float nn = dig[s] * di;
    a0 = fmaf(bf2f((unsigned short)(gg.x & 0xffff)), nn, a0);
    a1 = fmaf(bf2f((unsigned short)(gg.x >> 16)), nn, a1);
    a2 = fmaf(bf2f((unsigned short)(gg.y & 0xffff)), nn, a2);
    a3 = fmaf(bf2f((unsigned short)(gg.y >> 16)), nn, a3);
  }
  float4 bv = *(const float4*)&bias[c0];
  a0 += bv.x; a1 += bv.y; a2 += bv.z; a3 += bv.w;
  if (relu) {
    a0 = fmaxf(a0, 0.f); a1 = fmaxf(a1, 0.f);
    a2 = fmaxf(a2, 0.f); a3 = fmaxf(a3, 0.f);
  }
  if (OUTBF16) {
    uint2 o;
    o.x = ((unsigned)f2bf(a1) << 16) | f2bf(a0);
    o.y = ((unsigned)f2bf(a3) << 16) | f2bf(a2);
    *(uint2*)&((unsigned short*)outv)[(size_t)nglob * HD + c0] = o;
  } else {
    *(float4*)&((float*)outv)[(size_t)nglob * HD + c0] = make_float4(a0, a1, a2, a3);
  }
}

// ---------------- zscore (both graphs) ----------------

__global__ void k_colstats(const float* __restrict__ H, float* __restrict__ stats, int N,
                           int gridPer) {
  __shared__ float ss[256], sq[256];
  const int g = blockIdx.x / gridPer;
  const int blk = blockIdx.x % gridPer;
  const float* __restrict__ Hg = H + (size_t)g * N * HD;
  float* __restrict__ st = stats + g * 128;
  int t = threadIdx.x;
  int col = t & 63, grp = t >> 6;
  float s = 0.f, q = 0.f;
  for (int row = blk * 4 + grp; row < N; row += gridPer * 4) {
    float v = Hg[(size_t)row * HD + col];
    s += v;
    q += v * v;
  }
  ss[t] = s;
  sq[t] = q;
  __syncthreads();
  if (t < 64) {
    s = ss[t] + ss[t + 64] + ss[t + 128] + ss[t + 192];
    q = sq[t] + sq[t + 64] + sq[t + 128] + sq[t + 192];
    atomicAdd(&st[t], s);
    atomicAdd(&st[64 + t], q);
  }
}

__global__ void k_normalize(float* __restrict__ H, const float* __restrict__ stats, int N) {
  int i = blockIdx.x * blockDim.x + threadIdx.x;
  int total = 2 * N * HD;
  if (i >= total) return;
  int col = i & 63;
  const float* st = stats + (i >= N * HD ? 128 : 0);
  float sum = st[col], sumsq = st[64 + col];
  float mean = sum / (float)N;
  float var = (sumsq - sum * sum / (float)N) / (float)(N - 1);
  float r = rsqrtf(var);
  H[i] = (H[i] - mean) * r;
}

// ---------------- launch ----------------

extern "C" void kernel_launch(void* const* d_in, const int* in_sizes, int n_in,
                              void* d_out, int out_size, void* d_ws, size_t ws_size,
                              hipStream_t stream) {
  const int IN_DIM = 256;
  const float* X1 = (const float*)d_in[0];
  const float* X2 = (const float*)d_in[2];
  const int* EI1 = (const int*)d_in[1];
  const int* EI2 = (const int*)d_in[3];
  const float* W1 = (const float*)d_in[4];
  const float* b1 = (const float*)d_in[5];
  const float* W2 = (const float*)d_in[6];
  const float* b2 = (const float*)d_in[7];
  const int N = in_sizes[0] / IN_DIM;
  const int E = in_sizes[1] / 2;
  const int NB = (N + (1 << BKT_SHIFT) - 1) >> BKT_SHIFT;  // 98
  const int NBLK = (E + CH - 1) / CH;                      // 196

  char* ws = (char*)d_ws;
  size_t off = 0;
  auto carve = [&](size_t bytes) -> char* {
    char* p = ws + off;
    off += (bytes + 255) & ~(size_t)255;
    return p;
  };
  unsigned short* Hb = (unsigned short*)carve((size_t)2 * N * HD * 2);  // both graphs
  int* tmp = (int*)carve((size_t)2 * NBLK * CH * 4);
  int* recs = (int*)carve((size_t)2 * E * 4);
  char* zero_base = carve(256 * 4);  // stats[2][128]
  float* stats = (float*)zero_base;
  int* row_start = (int*)carve((size_t)2 * (N + 1) * 4);
  float* dinv = (float*)carve((size_t)2 * N * 4);
  int* bucket_base = (int*)carve((size_t)2 * (NB + 1) * 4);
  int* counts = (int*)carve((size_t)2 * NB * NBLK * 4);
  int* offsets = (int*)carve((size_t)2 * NB * NBLK * 4);
  unsigned short* Wf1 = (unsigned short*)carve(256 * 64 * 2);
  unsigned short* Wf2hi = (unsigned short*)carve(64 * 64 * 2);
  unsigned short* Wf2lo = (unsigned short*)carve(64 * 64 * 2);
  unsigned short* bufAgg = (unsigned short*)d_out;  // alias: dead before agg2 writes
  (void)ws_size; (void)n_in; (void)out_size;

  const int T = 256;
  const int gPer1 = (N + 63) / 64;        // 64-row gemm1 blocks, per graph
  const int gG2 = (2 * N + 63) / 64;      // gemm2 over 2N rows
  const int gAgg = (2 * N * 16 + T - 1) / T;
  const int gCS = 512;
  const int gElem = (2 * N * HD + T - 1) / T;
  const int gWp = (256 * 64 + 64 * 64 + T - 1) / T;  // 80

  (void)hipMemsetAsync(zero_base, 0, 256 * 4, stream);
  k_wprep<<<gWp, T, 0, stream>>>(W1, W2, Wf1, Wf2hi, Wf2lo);
  // FRONT: gemm1 (both graphs) || bin1 (both graphs) in one launch
  k_front<<<2 * gPer1 + 2 * NBLK, T, 0, stream>>>(X1, X2, Wf1, Hb, N, gPer1,
                                                  EI1, EI1 + E, EI2, EI2 + E,
                                                  tmp, counts, offsets, NB, NBLK, E);
  k_bscan<<<2, 128, 0, stream>>>(counts, bucket_base, row_start, NB, NBLK, N, E);
  k_bin2m<<<2 * NB, 1024, 0, stream>>>(tmp, counts, offsets, bucket_base, row_start,
                                       dinv, recs, N, NB, NBLK, E);

  // layer 1: agg -> bufAgg (bf16, in d_out)
  k_agg<1><<<gAgg, T, 0, stream>>>(Hb, recs, row_start, dinv, b1, bufAgg, N, E, 1);
  // layer 2: gemm over 2N rows -> agg -> d_out f32
  k_gemm2<<<gG2, T, 0, stream>>>(bufAgg, Wf2hi, Wf2lo, Hb, 2 * N);
  k_agg<0><<<gAgg, T, 0, stream>>>(Hb, recs, row_start, dinv, b2, d_out, N, E, 0);

  // zscore in place on d_out (per graph)
  k_colstats<<<2 * gCS, T, 0, stream>>>((float*)d_out, stats, N, gCS);
  k_normalize<<<gElem, T, 0, stream>>>((float*)d_out, stats, N);
}